// Round 24
// baseline (118.021 us; speedup 1.0000x reference)
//
#include <hip/hip_runtime.h>
#include <stdint.h>

#define IN_DIM 1024
#define OUT_DIM 1024
#define NROWS 8192
#define KD 3072            // k-major: k = (p-1)*1024 + i, p = 1..3 (k=0 folded into bias)
#define KHALF 1536         // split-K=2

#define BM 256
#define BN 256
#define BK 64
#define NTH (KHALF / BK)   // 24 K-tiles per half

typedef __bf16 bf16x8 __attribute__((ext_vector_type(8)));
typedef float f32x4 __attribute__((ext_vector_type(4)));
typedef unsigned short us8 __attribute__((ext_vector_type(8)));
typedef unsigned int u32;

#define AS1 __attribute__((address_space(1)))
#define AS3 __attribute__((address_space(3)))

__device__ __forceinline__ unsigned short f2bf(float f) {
    u32 u = __builtin_bit_cast(u32, f);
    u32 r = (u + 0x7fffu + ((u >> 16) & 1u)) >> 16;   // RNE, finite inputs
    return (unsigned short)r;
}

__device__ __forceinline__ bf16x8 ld8(const unsigned short* p) {
    return __builtin_bit_cast(bf16x8, *reinterpret_cast<const us8*>(p));
}

// ---- merged prep (one dispatch, r21-verified):
// blocks [0, 8192):    powers of x -> bf16 A[NROWS][KD] (k-major)
// blocks [8192, 9216): coeffs -> bf16 B[OUT_DIM][KD] (k-major), c0 -> bias2
__global__ __launch_bounds__(256) void taylor_prep(const float* __restrict__ x,
                                                   const float* __restrict__ c,
                                                   const float* __restrict__ bias,
                                                   unsigned short* __restrict__ A,
                                                   unsigned short* __restrict__ B,
                                                   float* __restrict__ bias2) {
    if (blockIdx.x < 8192) {
        int t = blockIdx.x * 256 + threadIdx.x;           // each handles 4 x values
        int n = t >> 8;                                   // 256 float4 per row
        int i4 = (t & 255) * 4;
        float4 v = reinterpret_cast<const float4*>(x)[t];
        unsigned short* An = A + (size_t)n * KD + i4;
        float xs[4] = {v.x, v.y, v.z, v.w};
        unsigned short b1[4], b2[4], b3[4];
#pragma unroll
        for (int j = 0; j < 4; ++j) {
            float x1 = xs[j], x2 = x1 * x1, x3 = x2 * x1;
            b1[j] = f2bf(x1); b2[j] = f2bf(x2); b3[j] = f2bf(x3);
        }
        ushort4 p1 = {b1[0], b1[1], b1[2], b1[3]};
        ushort4 p2 = {b2[0], b2[1], b2[2], b2[3]};
        ushort4 p3 = {b3[0], b3[1], b3[2], b3[3]};
        *reinterpret_cast<ushort4*>(An)        = p1;
        *reinterpret_cast<ushort4*>(An + 1024) = p2;
        *reinterpret_cast<ushort4*>(An + 2048) = p3;
    } else {
        const int o = blockIdx.x - 8192;
        const float4* row = reinterpret_cast<const float4*>(c + (size_t)o * (IN_DIM * 4));
        unsigned short* Bo = B + (size_t)o * KD;
        float s = 0.f;
        for (int i = threadIdx.x; i < IN_DIM; i += 256) {
            float4 v = row[i];            // {c0, c1, c2, c3} for (o, i)
            s += v.x;
            Bo[i]        = f2bf(v.y);
            Bo[1024 + i] = f2bf(v.z);
            Bo[2048 + i] = f2bf(v.w);
        }
#pragma unroll
        for (int off = 32; off; off >>= 1) s += __shfl_down(s, off);
        __shared__ float red[4];
        if ((threadIdx.x & 63) == 0) red[threadIdx.x >> 6] = s;
        __syncthreads();
        if (threadIdx.x == 0) bias2[o] = bias[o] + red[0] + red[1] + red[2] + red[3];
    }
}

// ---- main GEMM (m201-faithful 256x256, split-K=2): C += A_half * B_half^T ----
// 8 waves 2Mx4N (wave 128x64). LDS 128 KiB = 2buf x (A 32K + B 32K).
// Per tile: 8 stage units (B0-3, A0-3; 1 gload_lds/thread each) issued 2/phase
// during the PREVIOUS tile, earliest-needed-first: ph0{B0,B1} ph1{B2,B3}
// ph2{A0,A2} ph3{A1,A3}. 4 phases = C-quadrants: ph0 m0-3xn0-1 (12 ds_reads),
// ph1 m0-3xn2-3 (4), ph2 m4-7xn2-3 (8), ph3 m4-7xn0-1 (0). Counted waits on
// closing barriers: vmcnt(4) after ph1 (forces THIS tile's A1,A3; leaves 4),
// vmcnt(2) after ph3 (forces next tile's B0-3,A0,A2; leaves A1,A3 flying) —
// never a mid-loop drain (r22's fatal flaw). Two barriers/phase (m201).
// T2 swizzle pair (conflicts=0, r&7==lane&7 invariant). Epilogue: atomicAdd
// onto memset-zeroed C (+bias2 on kz==0; r22-verified correct).
__global__ __launch_bounds__(512, 1) void taylor_gemm(
    const unsigned short* __restrict__ A,   // bf16 [NROWS][KD]
    const unsigned short* __restrict__ B,   // bf16 [OUT_DIM][KD]
    const float* __restrict__ bias2,
    float* __restrict__ C) {
    __shared__ alignas(16) unsigned short sA[2][BM * BK];  // 2 x 32 KiB
    __shared__ alignas(16) unsigned short sB[2][BN * BK];  // 2 x 32 KiB

    const int tid = threadIdx.x;
    const int lane = tid & 63;
    const int wid = tid >> 6;       // 0..7
    const int wr = wid >> 2;        // 0..1  (M half: 128 rows)
    const int wc = wid & 3;         // 0..3  (N quarter: 64 cols)
    const int gx = blockIdx.x, gy = blockIdx.y, kz = blockIdx.z;

    // ---- staging: unit u covers rows [u*64, u*64+64); wave stages 8 rows ----
    const char* Ab = (const char*)A;
    const char* Bb = (const char*)B;
    const int cs = ((lane & 7) ^ (lane >> 3)) * 8;   // swizzled source col (ushort)
    const size_t kzoff = (size_t)kz * KHALF * 2;
    size_t aSrc[4], bSrc[4];
    int uDst[4];
#pragma unroll
    for (int u = 0; u < 4; ++u) {
        int rrow = u * 64 + wid * 8 + (lane >> 3);   // 0..255 within tile
        aSrc[u] = ((size_t)(gx * BM + rrow) * KD + cs) * 2 + kzoff;
        bSrc[u] = ((size_t)(gy * BN + rrow) * KD + cs) * 2 + kzoff;
        uDst[u] = (u * 64 + wid * 8) * BK;           // wave-uniform base
    }

    auto stage_A = [&](int b, int kt, int u) {
        __builtin_amdgcn_global_load_lds(
            (const AS1 void*)(Ab + aSrc[u] + (size_t)kt * (BK * 2)),
            (AS3 void*)(&sA[b][uDst[u]]), 16, 0, 0);
    };
    auto stage_B = [&](int b, int kt, int u) {
        __builtin_amdgcn_global_load_lds(
            (const AS1 void*)(Bb + bSrc[u] + (size_t)kt * (BK * 2)),
            (AS3 void*)(&sB[b][uDst[u]]), 16, 0, 0);
    };

    // swizzled fragment read bases (ushort index), per ks:
    // A row r = wr*128 + m*16 + (lane&15); B row r = wc*64 + n*16 + (lane&15)
    // (r&7 == lane&7); slot s = ks*4+(lane>>4); addr = r*64 + (s^(lane&7))*8
    int aBase[2], bBase[2];
#pragma unroll
    for (int ks = 0; ks < 2; ++ks) {
        int sw = ((ks * 4 + (lane >> 4)) ^ (lane & 7)) * 8;
        aBase[ks] = (wr * 128 + (lane & 15)) * BK + sw;
        bBase[ks] = (wc * 64 + (lane & 15)) * BK + sw;
    }

    f32x4 acc[8][4] = {};

    // prologue: tile 0 units in steady-state order -> buf 0
    stage_B(0, 0, 0); stage_B(0, 0, 1); stage_B(0, 0, 2); stage_B(0, 0, 3);
    stage_A(0, 0, 0); stage_A(0, 0, 2); stage_A(0, 0, 1); stage_A(0, 0, 3);
    asm volatile("s_waitcnt vmcnt(2)" ::: "memory");   // force B0-3,A0,A2
    __builtin_amdgcn_s_barrier();
    __builtin_amdgcn_sched_barrier(0);

    for (int kt = 0; kt < NTH; ++kt) {
        const int d = kt & 1, nd = d ^ 1;
        const bool doStage = (kt + 1 < NTH);
        const unsigned short* sAc = &sA[d][0];
        const unsigned short* sBc = &sB[d][0];

        bf16x8 bf01[2][2], bf23[2][2], af03[4][2], af47[4][2];

        // ---- ph0: read A m0-3 (8) + B n0-1 (4) || stage B0,B1(kt+1) ----
#pragma unroll
        for (int mi = 0; mi < 4; ++mi)
#pragma unroll
            for (int ks = 0; ks < 2; ++ks)
                af03[mi][ks] = ld8(&sAc[aBase[ks] + mi * 16 * BK]);
#pragma unroll
        for (int n = 0; n < 2; ++n)
#pragma unroll
            for (int ks = 0; ks < 2; ++ks)
                bf01[n][ks] = ld8(&sBc[bBase[ks] + n * 16 * BK]);
        if (doStage) { stage_B(nd, kt + 1, 0); stage_B(nd, kt + 1, 1); }
        __builtin_amdgcn_s_barrier();
        asm volatile("s_waitcnt lgkmcnt(0)" ::: "memory");
        __builtin_amdgcn_sched_barrier(0);   // rule #18
        __builtin_amdgcn_s_setprio(1);
#pragma unroll
        for (int mi = 0; mi < 4; ++mi)
#pragma unroll
            for (int n = 0; n < 2; ++n)
#pragma unroll
                for (int ks = 0; ks < 2; ++ks)
                    acc[mi][n] = __builtin_amdgcn_mfma_f32_16x16x32_bf16(
                        af03[mi][ks], bf01[n][ks], acc[mi][n], 0, 0, 0);
        __builtin_amdgcn_s_setprio(0);
        __builtin_amdgcn_s_barrier();
        __builtin_amdgcn_sched_barrier(0);

        // ---- ph1: read B n2-3 (4) || stage B2,B3(kt+1) ----
#pragma unroll
        for (int n = 0; n < 2; ++n)
#pragma unroll
            for (int ks = 0; ks < 2; ++ks)
                bf23[n][ks] = ld8(&sBc[bBase[ks] + (2 + n) * 16 * BK]);
        if (doStage) { stage_B(nd, kt + 1, 2); stage_B(nd, kt + 1, 3); }
        __builtin_amdgcn_s_barrier();
        asm volatile("s_waitcnt lgkmcnt(0)" ::: "memory");
        __builtin_amdgcn_sched_barrier(0);
        __builtin_amdgcn_s_setprio(1);
#pragma unroll
        for (int mi = 0; mi < 4; ++mi)
#pragma unroll
            for (int n = 0; n < 2; ++n)
#pragma unroll
                for (int ks = 0; ks < 2; ++ks)
                    acc[mi][2 + n] = __builtin_amdgcn_mfma_f32_16x16x32_bf16(
                        af03[mi][ks], bf23[n][ks], acc[mi][2 + n], 0, 0, 0);
        __builtin_amdgcn_s_setprio(0);
        // closing wait: force THIS tile's A1,A3 (oldest outstanding)
        if (doStage) asm volatile("s_waitcnt vmcnt(4)" ::: "memory");
        else         asm volatile("s_waitcnt vmcnt(0)" ::: "memory");
        __builtin_amdgcn_s_barrier();
        __builtin_amdgcn_sched_barrier(0);

        // ---- ph2: read A m4-7 (8) || stage A0,A2(kt+1) ----
#pragma unroll
        for (int mi = 0; mi < 4; ++mi)
#pragma unroll
            for (int ks = 0; ks < 2; ++ks)
                af47[mi][ks] = ld8(&sAc[aBase[ks] + (4 + mi) * 16 * BK]);
        if (doStage) { stage_A(nd, kt + 1, 0); stage_A(nd, kt + 1, 2); }
        __builtin_amdgcn_s_barrier();
        asm volatile("s_waitcnt lgkmcnt(0)" ::: "memory");
        __builtin_amdgcn_sched_barrier(0);
        __builtin_amdgcn_s_setprio(1);
#pragma unroll
        for (int mi = 0; mi < 4; ++mi)
#pragma unroll
            for (int n = 0; n < 2; ++n)
#pragma unroll
                for (int ks = 0; ks < 2; ++ks)
                    acc[4 + mi][2 + n] = __builtin_amdgcn_mfma_f32_16x16x32_bf16(
                        af47[mi][ks], bf23[n][ks], acc[4 + mi][2 + n], 0, 0, 0);
        __builtin_amdgcn_s_setprio(0);
        __builtin_amdgcn_s_barrier();
        __builtin_amdgcn_sched_barrier(0);

        // ---- ph3: no reads || stage A1,A3(kt+1) ----
        if (doStage) { stage_A(nd, kt + 1, 1); stage_A(nd, kt + 1, 3); }
        __builtin_amdgcn_s_barrier();
        __builtin_amdgcn_s_setprio(1);
#pragma unroll
        for (int mi = 0; mi < 4; ++mi)
#pragma unroll
            for (int n = 0; n < 2; ++n)
#pragma unroll
                for (int ks = 0; ks < 2; ++ks)
                    acc[4 + mi][n] = __builtin_amdgcn_mfma_f32_16x16x32_bf16(
                        af47[mi][ks], bf01[n][ks], acc[4 + mi][n], 0, 0, 0);
        __builtin_amdgcn_s_setprio(0);
        // closing wait: force NEXT tile's B0-3,A0,A2 (leave A1,A3 in flight)
        if (doStage) asm volatile("s_waitcnt vmcnt(2)" ::: "memory");
        else         asm volatile("s_waitcnt vmcnt(0)" ::: "memory");
        __builtin_amdgcn_s_barrier();
        __builtin_amdgcn_sched_barrier(0);
    }

    // epilogue: atomicAdd onto zeroed C; kz==0 contributes bias2.
    // C/D layout col = lane&15, row = (lane>>4)*4 + r
    const int colBase = gy * BN + wc * 64 + (lane & 15);
    const int rowBase = gx * BM + wr * 128 + (lane >> 4) * 4;
#pragma unroll
    for (int n = 0; n < 4; ++n) {
        int col = colBase + n * 16;
        float bv = (kz == 0) ? bias2[col] : 0.f;
#pragma unroll
        for (int m = 0; m < 8; ++m) {
            int row = rowBase + m * 16;
#pragma unroll
            for (int r = 0; r < 4; ++r)
                atomicAdd(&C[(size_t)(row + r) * OUT_DIM + col], acc[m][n][r] + bv);
        }
    }
}

// ---- fallback (ws too small): fp32 LDS-staged, correct but slow ----
__global__ void taylor_naive(const float* __restrict__ x, const float* __restrict__ coeffs,
                             const float* __restrict__ bias, float* __restrict__ out) {
    int n = blockIdx.x;
    __shared__ float P[IN_DIM * 4];
    for (int i = threadIdx.x; i < IN_DIM; i += blockDim.x) {
        float xv = x[(size_t)n * IN_DIM + i];
        P[i * 4 + 0] = 1.f;
        P[i * 4 + 1] = xv;
        P[i * 4 + 2] = xv * xv;
        P[i * 4 + 3] = xv * xv * xv;
    }
    __syncthreads();
    for (int o = threadIdx.x; o < OUT_DIM; o += blockDim.x) {
        float s = bias[o];
        const float* c = coeffs + (size_t)o * (IN_DIM * 4);
        for (int i = 0; i < IN_DIM; ++i) {
            float4 cv = *reinterpret_cast<const float4*>(c + i * 4);
            s += cv.x * P[i * 4 + 0] + cv.y * P[i * 4 + 1] +
                 cv.z * P[i * 4 + 2] + cv.w * P[i * 4 + 3];
        }
        out[(size_t)n * OUT_DIM + o] = s;
    }
}

extern "C" void kernel_launch(void* const* d_in, const int* in_sizes, int n_in,
                              void* d_out, int out_size, void* d_ws, size_t ws_size,
                              hipStream_t stream) {
    const float* x = (const float*)d_in[0];
    const float* coeffs = (const float*)d_in[1];
    const float* bias = (const float*)d_in[2];
    float* out = (float*)d_out;

    const size_t needA = (size_t)NROWS * KD * 2;     // 48 MiB
    const size_t needB = (size_t)OUT_DIM * KD * 2;   // 6 MiB
    const size_t needBias = OUT_DIM * sizeof(float); // 4 KiB

    if (ws_size >= needA + needB + needBias) {
        unsigned short* A = (unsigned short*)d_ws;
        unsigned short* B = (unsigned short*)((char*)d_ws + needA);
        float* bias2 = (float*)((char*)d_ws + needA + needB);
        hipMemsetAsync(out, 0, (size_t)out_size * sizeof(float), stream);
        taylor_prep<<<8192 + 1024, 256, 0, stream>>>(x, coeffs, bias, A, B, bias2);
        dim3 grid(NROWS / BM, OUT_DIM / BN, 2);   // (32, 4, 2) = 256 blocks, 1/CU
        taylor_gemm<<<grid, 512, 0, stream>>>(A, B, bias2, out);
    } else {
        taylor_naive<<<NROWS, 256, 0, stream>>>(x, coeffs, bias, out);
    }
}

// Round 25
// 72.504 us; speedup vs baseline: 1.6278x; 1.6278x over previous
//
#include <hip/hip_runtime.h>
#include <stdint.h>

#define IN_DIM 1024
#define OUT_DIM 1024
#define NROWS 8192
#define KD 3072            // k-major: k = (p-1)*1024 + i, p = 1..3 (k=0 folded into bias)

#define BM 256
#define BN 128
#define BK 64
#define NT (KD / BK)       // 48 K-tiles

typedef __bf16 bf16x8 __attribute__((ext_vector_type(8)));
typedef float f32x4 __attribute__((ext_vector_type(4)));
typedef unsigned short us8 __attribute__((ext_vector_type(8)));
typedef unsigned int u32;

#define AS1 __attribute__((address_space(1)))
#define AS3 __attribute__((address_space(3)))

__device__ __forceinline__ unsigned short f2bf(float f) {
    u32 u = __builtin_bit_cast(u32, f);
    u32 r = (u + 0x7fffu + ((u >> 16) & 1u)) >> 16;   // RNE, finite inputs
    return (unsigned short)r;
}

__device__ __forceinline__ bf16x8 ld8(const unsigned short* p) {
    return __builtin_bit_cast(bf16x8, *reinterpret_cast<const us8*>(p));
}

// ---- merged prep (one dispatch, r13/r21-verified):
// blocks [0, 8192):    powers of x -> bf16 A[NROWS][KD] (k-major)
// blocks [8192, 9216): coeffs -> bf16 B[OUT_DIM][KD] (k-major), c0 -> bias2
__global__ __launch_bounds__(256) void taylor_prep(const float* __restrict__ x,
                                                   const float* __restrict__ c,
                                                   const float* __restrict__ bias,
                                                   unsigned short* __restrict__ A,
                                                   unsigned short* __restrict__ B,
                                                   float* __restrict__ bias2) {
    if (blockIdx.x < 8192) {
        int t = blockIdx.x * 256 + threadIdx.x;           // each handles 4 x values
        int n = t >> 8;                                   // 256 float4 per row
        int i4 = (t & 255) * 4;
        float4 v = reinterpret_cast<const float4*>(x)[t];
        unsigned short* An = A + (size_t)n * KD + i4;
        float xs[4] = {v.x, v.y, v.z, v.w};
        unsigned short b1[4], b2[4], b3[4];
#pragma unroll
        for (int j = 0; j < 4; ++j) {
            float x1 = xs[j], x2 = x1 * x1, x3 = x2 * x1;
            b1[j] = f2bf(x1); b2[j] = f2bf(x2); b3[j] = f2bf(x3);
        }
        ushort4 p1 = {b1[0], b1[1], b1[2], b1[3]};
        ushort4 p2 = {b2[0], b2[1], b2[2], b2[3]};
        ushort4 p3 = {b3[0], b3[1], b3[2], b3[3]};
        *reinterpret_cast<ushort4*>(An)        = p1;
        *reinterpret_cast<ushort4*>(An + 1024) = p2;
        *reinterpret_cast<ushort4*>(An + 2048) = p3;
    } else {
        const int o = blockIdx.x - 8192;
        const float4* row = reinterpret_cast<const float4*>(c + (size_t)o * (IN_DIM * 4));
        unsigned short* Bo = B + (size_t)o * KD;
        float s = 0.f;
        for (int i = threadIdx.x; i < IN_DIM; i += 256) {
            float4 v = row[i];            // {c0, c1, c2, c3} for (o, i)
            s += v.x;
            Bo[i]        = f2bf(v.y);
            Bo[1024 + i] = f2bf(v.z);
            Bo[2048 + i] = f2bf(v.w);
        }
#pragma unroll
        for (int off = 32; off; off >>= 1) s += __shfl_down(s, off);
        __shared__ float red[4];
        if ((threadIdx.x & 63) == 0) red[threadIdx.x >> 6] = s;
        __syncthreads();
        if (threadIdx.x == 0) bias2[o] = bias[o] + red[0] + red[1] + red[2] + red[3];
    }
}

// ---- main GEMM: C = A[M][KD] * B[N][KD]^T + bias2 ----
// SESSION-BEST / FINAL (r15/r19/r21/r23: 55.2us GEMM, 933 TF, x4 reproduced):
// BM=256 BN=128 BK=64, grid 256 (1 block/CU), 512 thr / 8 waves as 4M x 2N
// (wave tile 64x64 — duplication-optimal). Triple-buffered LDS (144 KiB),
// stage-2-ahead with vmcnt(6) counted once per tile (tile kt+1's 6 units
// stay in flight across barriers), 2 phases x 16 MFMA with phase-closing
// barriers, T2 XOR-swizzle pair (SQ_LDS_BANK_CONFLICT=0), setprio on MFMA.
// Verified dead ends (do not revisit): A-direct (r11), B-direct (r14/r18),
// 1 wave/SIMD (r17), fused in-register A-gen (r6-r9), fused-powers 32-col
// supertiles (r20), split-K 256^2 both simplified and m201-faithful
// (r22/r24: ~94us, wave 128x64 A-dup + no prefetch slack at 2buf/1-blk),
// 2-blocks/CU VGPR cap (r7 spills), cross-half-tile reg pipe (r16),
// 2Mx4N waves (r13).
__global__ __launch_bounds__(512, 1) void taylor_gemm(
    const unsigned short* __restrict__ A,   // bf16 [NROWS][KD]
    const unsigned short* __restrict__ B,   // bf16 [OUT_DIM][KD]
    const float* __restrict__ bias2,
    float* __restrict__ C) {
    __shared__ alignas(16) unsigned short sA[3][BM * BK];  // 3 x 32 KiB
    __shared__ alignas(16) unsigned short sB[3][BN * BK];  // 3 x 16 KiB

    const int tid = threadIdx.x;
    const int lane = tid & 63;
    const int wid = tid >> 6;       // 0..7
    const int wr = wid >> 1;        // 0..3  (M quarter: 64 rows)
    const int wc = wid & 1;         // 0..1  (N half: 64 cols)
    const int gx = blockIdx.x, gy = blockIdx.y;

    // ---- staging: 6 gld_lds units/wave/tile (A:4, B:2), T2 source swizzle ----
    const char* Ab = (const char*)A;
    const char* Bb = (const char*)B;
    const int cs = ((lane & 7) ^ (lane >> 3)) * 8;   // swizzled source col (ushort)
    size_t aSrc[4], bSrc[2];
    int aDst[4], bDst[2];
#pragma unroll
    for (int u = 0; u < 4; ++u) {
        int row = gx * BM + u * 64 + wid * 8 + (lane >> 3);
        aSrc[u] = ((size_t)row * KD + cs) * 2;
        aDst[u] = (u * 64 + wid * 8) * BK;
    }
#pragma unroll
    for (int u = 0; u < 2; ++u) {
        int row = gy * BN + u * 64 + wid * 8 + (lane >> 3);
        bSrc[u] = ((size_t)row * KD + cs) * 2;
        bDst[u] = (u * 64 + wid * 8) * BK;
    }

    auto stage_unit = [&](int b, int kt, int u) {
        size_t koff = (size_t)kt * (BK * 2);
        if (u < 4)
            __builtin_amdgcn_global_load_lds(
                (const AS1 void*)(Ab + aSrc[u] + koff),
                (AS3 void*)(&sA[b][aDst[u]]), 16, 0, 0);
        else
            __builtin_amdgcn_global_load_lds(
                (const AS1 void*)(Bb + bSrc[u - 4] + koff),
                (AS3 void*)(&sB[b][bDst[u - 4]]), 16, 0, 0);
    };

    // swizzled fragment read bases (ushort index), per ks:
    // A row r = wr*64 + m*16 + (lane&15); B row r = wc*64 + n*16 + (lane&15)
    // (r&7 == lane&7); slot s = ks*4+(lane>>4); addr = r*64 + (s^(lane&7))*8
    int aSw[2], bSw[2];
#pragma unroll
    for (int ks = 0; ks < 2; ++ks) {
        int sw = ((ks * 4 + (lane >> 4)) ^ (lane & 7)) * 8;
        aSw[ks] = (wr * 64 + (lane & 15)) * BK + sw;
        bSw[ks] = (wc * 64 + (lane & 15)) * BK + sw;
    }

    f32x4 acc[4][4] = {};

    // prologue: stage tiles 0,1 -> bufs 0,1 (12 units outstanding/wave)
#pragma unroll
    for (int u = 0; u < 6; ++u) stage_unit(0, 0, u);
#pragma unroll
    for (int u = 0; u < 6; ++u) stage_unit(1, 1, u);

    for (int kt = 0; kt < NT; ++kt) {
        const int cb = kt % 3;
        const int nb = (kt + 2) % 3;
        // counted wait: tile kt's 6 units landed; tile kt+1's 6 stay in flight
        if (kt < NT - 1) asm volatile("s_waitcnt vmcnt(6)" ::: "memory");
        else             asm volatile("s_waitcnt vmcnt(0)" ::: "memory");
        __builtin_amdgcn_s_barrier();        // cross-wave staging visibility
        __builtin_amdgcn_sched_barrier(0);

        const unsigned short* sAc = &sA[cb][0];
        const unsigned short* sBc = &sB[cb][0];
        const bool doStage = (kt < NT - 2);

        // ---- phase 0: B frags (8) + A frags m0,m1 (4) || stage 3 -> 16 MFMA ----
        bf16x8 bf[4][2], af[2][2];
#pragma unroll
        for (int n = 0; n < 4; ++n)
#pragma unroll
            for (int ks = 0; ks < 2; ++ks)
                bf[n][ks] = ld8(&sBc[bSw[ks] + n * 16 * BK]);
#pragma unroll
        for (int mi = 0; mi < 2; ++mi)
#pragma unroll
            for (int ks = 0; ks < 2; ++ks)
                af[mi][ks] = ld8(&sAc[aSw[ks] + mi * 16 * BK]);
        if (doStage) {
            stage_unit(nb, kt + 2, 0);
            stage_unit(nb, kt + 2, 4);
            stage_unit(nb, kt + 2, 1);
        }
        asm volatile("s_waitcnt lgkmcnt(0)" ::: "memory");
        __builtin_amdgcn_sched_barrier(0);   // rule #18
        __builtin_amdgcn_s_setprio(1);
#pragma unroll
        for (int mi = 0; mi < 2; ++mi)
#pragma unroll
            for (int n = 0; n < 4; ++n)
#pragma unroll
                for (int ks = 0; ks < 2; ++ks)
                    acc[mi][n] = __builtin_amdgcn_mfma_f32_16x16x32_bf16(
                        af[mi][ks], bf[n][ks], acc[mi][n], 0, 0, 0);
        __builtin_amdgcn_s_setprio(0);
        __builtin_amdgcn_s_barrier();        // phase-closing barrier (role split)
        __builtin_amdgcn_sched_barrier(0);

        // ---- phase 1: A frags m2,m3 (4) || stage 3 -> 16 MFMA ----
        bf16x8 af2[2][2];
#pragma unroll
        for (int mi = 0; mi < 2; ++mi)
#pragma unroll
            for (int ks = 0; ks < 2; ++ks)
                af2[mi][ks] = ld8(&sAc[aSw[ks] + (2 + mi) * 16 * BK]);
        if (doStage) {
            stage_unit(nb, kt + 2, 5);
            stage_unit(nb, kt + 2, 2);
            stage_unit(nb, kt + 2, 3);
        }
        asm volatile("s_waitcnt lgkmcnt(0)" ::: "memory");
        __builtin_amdgcn_sched_barrier(0);
        __builtin_amdgcn_s_setprio(1);
#pragma unroll
        for (int mi = 0; mi < 2; ++mi)
#pragma unroll
            for (int n = 0; n < 4; ++n)
#pragma unroll
                for (int ks = 0; ks < 2; ++ks)
                    acc[2 + mi][n] = __builtin_amdgcn_mfma_f32_16x16x32_bf16(
                        af2[mi][ks], bf[n][ks], acc[2 + mi][n], 0, 0, 0);
        __builtin_amdgcn_s_setprio(0);
        __builtin_amdgcn_s_barrier();        // phase-closing barrier
        __builtin_amdgcn_sched_barrier(0);
    }

    // epilogue: C/D layout col = lane&15, row = (lane>>4)*4 + r
    const int colBase = gy * BN + wc * 64 + (lane & 15);
    const int rowBase = gx * BM + wr * 64 + (lane >> 4) * 4;
#pragma unroll
    for (int n = 0; n < 4; ++n) {
        int col = colBase + n * 16;
        float bv = bias2[col];
#pragma unroll
        for (int m = 0; m < 4; ++m) {
            int row = rowBase + m * 16;
#pragma unroll
            for (int r = 0; r < 4; ++r)
                C[(size_t)(row + r) * OUT_DIM + col] = acc[m][n][r] + bv;
        }
    }
}

// ---- fallback (ws too small): fp32 LDS-staged, correct but slow ----
__global__ void taylor_naive(const float* __restrict__ x, const float* __restrict__ coeffs,
                             const float* __restrict__ bias, float* __restrict__ out) {
    int n = blockIdx.x;
    __shared__ float P[IN_DIM * 4];
    for (int i = threadIdx.x; i < IN_DIM; i += blockDim.x) {
        float xv = x[(size_t)n * IN_DIM + i];
        P[i * 4 + 0] = 1.f;
        P[i * 4 + 1] = xv;
        P[i * 4 + 2] = xv * xv;
        P[i * 4 + 3] = xv * xv * xv;
    }
    __syncthreads();
    for (int o = threadIdx.x; o < OUT_DIM; o += blockDim.x) {
        float s = bias[o];
        const float* c = coeffs + (size_t)o * (IN_DIM * 4);
        for (int i = 0; i < IN_DIM; ++i) {
            float4 cv = *reinterpret_cast<const float4*>(c + i * 4);
            s += cv.x * P[i * 4 + 0] + cv.y * P[i * 4 + 1] +
                 cv.z * P[i * 4 + 2] + cv.w * P[i * 4 + 3];
        }
        out[(size_t)n * OUT_DIM + o] = s;
    }
}

extern "C" void kernel_launch(void* const* d_in, const int* in_sizes, int n_in,
                              void* d_out, int out_size, void* d_ws, size_t ws_size,
                              hipStream_t stream) {
    const float* x = (const float*)d_in[0];
    const float* coeffs = (const float*)d_in[1];
    const float* bias = (const float*)d_in[2];
    float* out = (float*)d_out;

    const size_t needA = (size_t)NROWS * KD * 2;     // 48 MiB
    const size_t needB = (size_t)OUT_DIM * KD * 2;   // 6 MiB
    const size_t needBias = OUT_DIM * sizeof(float); // 4 KiB

    if (ws_size >= needA + needB + needBias) {
        unsigned short* A = (unsigned short*)d_ws;
        unsigned short* B = (unsigned short*)((char*)d_ws + needA);
        float* bias2 = (float*)((char*)d_ws + needA + needB);
        taylor_prep<<<8192 + 1024, 256, 0, stream>>>(x, coeffs, bias, A, B, bias2);
        dim3 grid(NROWS / BM, OUT_DIM / BN);   // (32, 8) = 256 blocks, 1/CU
        taylor_gemm<<<grid, 512, 0, stream>>>(A, B, bias2, out);
    } else {
        taylor_naive<<<NROWS, 256, 0, stream>>>(x, coeffs, bias, out);
    }
}